// Round 5
// baseline (691.778 us; speedup 1.0000x reference)
//
#include <hip/hip_runtime.h>
#include <hip/hip_bf16.h>

namespace {

constexpr int kT = 51;      // input timesteps
constexpr int kOut = 20;    // decoder steps
constexpr float kL2E  = 1.4426950408889634f;   // log2(e)
constexpr float kL2E2 = 2.8853900817779268f;   // 2*log2(e)

typedef __attribute__((ext_vector_type(8))) short bf16x8;
typedef __attribute__((ext_vector_type(4))) float f32x4;

union FragU {
    bf16x8 v;
    unsigned long long u64[2];
    unsigned int u32[4];
    unsigned short s[8];
};

__device__ __forceinline__ unsigned short f2bf(float x) {
    union { float f; unsigned int u; } v;
    v.f = x;
    unsigned int r = (v.u + 0x7fffu + ((v.u >> 16) & 1u)) >> 16;
    return (unsigned short)r;
}

// pack two floats to bf16x2 (low=bf(a), high=bf(b)): 2x v_add_u32 + v_perm_b32
__device__ __forceinline__ unsigned int packbf(float a, float b) {
    union { float f; unsigned int u; } ua, ub;
    ua.f = a; ub.f = b;
    return __builtin_amdgcn_perm(ub.u + 0x8000u, ua.u + 0x8000u, 0x07060302u);
}

// GRU enc-dec, 4-way unit split. Block = 256 thr = 4 waves = 1 team handling
// 16 batch rows (b = blockIdx*16 + (lane&15)). Wave w owns hidden units
// [16w, 16w+16) -> weight row-tiles tau: r=w, z=4+w, n=8+w (one 16-row tile
// per gate). All waves need FULL h as the MFMA B operand -> h' slices are
// exchanged via double-buffered LDS with one __syncthreads per step.
// MFMA 16x16x32 layouts: A lane(q,i)=A[m=i][k=8q+j]; B lane(q,i)=B[k=8q+j][n=i];
// C lane(q,i)=C[row=4q+r][col=i]. Weights pre-scaled by log2e (r,z) / 2log2e
// (n) so activations use raw v_exp_f32. Shared-rcp computes r,z sigmoids with
// one v_rcp: rp=rcp((1+a)(1+b)), r=rp*(1+b), z=rp*(1+a).
__global__ __launch_bounds__(256, 4) void gru_encdec(
    const float* __restrict__ input,
    const float* __restrict__ eWih, const float* __restrict__ eWhh,
    const float* __restrict__ ebih, const float* __restrict__ ebhh,
    const float* __restrict__ dWih, const float* __restrict__ dWhh,
    const float* __restrict__ dbih, const float* __restrict__ dbhh,
    const float* __restrict__ linW, const float* __restrict__ linb,
    float* __restrict__ out)
{
    // h exchange: [dbuf][16 rows x 64 units, stride 68 bf16]
    __shared__ __align__(16) unsigned short hbuf[2][16 * 68];
    // decoder output staging: 16 rows x 80 floats, stride 84
    __shared__ __align__(16) float sout[16 * 84];

    const int lane = (int)(threadIdx.x & 63u);
    const int w = (int)(threadIdx.x >> 6u);   // unit-quarter owner
    const int q = lane >> 4;
    const int i = lane & 15;
    const long b = (long)blockIdx.x * 16 + i;
    const float* __restrict__ xrow = input + b * (kT * 4);
    const bool q0 = (q == 0);

    // Per-wave weight fragments: l = 0 (r), 1 (z), 2 (n); tau = 4*l + w
    bf16x8 WA[3][2];     // Whh frags, [l][K-half]
    bf16x8 WAUG[3];      // [Wih(4) | bias | 0...] frags (q0 lanes only)
    f32x4 bhhn4;         // bhh_n * 2l2e as C-init
    float hprev[4];      // fp32 h, [r] = h[b=i][u=16w+4q+r]
    bf16x8 bh0 = {0, 0, 0, 0, 0, 0, 0, 0};  // B-frag h[b=i][k=8q+j]
    bf16x8 bh1 = {0, 0, 0, 0, 0, 0, 0, 0};  // B-frag h[b=i][k=32+8q+j]
    float px[4];
    const f32x4 z4 = {0.f, 0.f, 0.f, 0.f};
    int sel = 0;  // LDS h dbuf selector (uniform across block)

    auto load_whh = [&](const float* __restrict__ Whh) {
#pragma unroll
        for (int l = 0; l < 3; ++l) {
            const int tau = 4 * l + w;
            const float sc = (l < 2) ? kL2E : kL2E2;
#pragma unroll
            for (int f = 0; f < 2; ++f) {
                const float* ptr = Whh + (tau * 16 + i) * 64 + f * 32 + q * 8;
                FragU fu;
#pragma unroll
                for (int j = 0; j < 8; ++j) fu.s[j] = f2bf(ptr[j] * sc);
                WA[l][f] = fu.v;
            }
        }
    };

    auto load_aug = [&](const float* __restrict__ Wih,
                        const float* __restrict__ bih,
                        const float* __restrict__ bhh) {
#pragma unroll
        for (int l = 0; l < 3; ++l) {
            const int tau = 4 * l + w;
            const float sc = (l < 2) ? kL2E : kL2E2;
            FragU fu;
            fu.u64[0] = 0; fu.u64[1] = 0;
            if (q0) {
                int j = tau * 16 + i;
#pragma unroll
                for (int d = 0; d < 4; ++d) fu.s[d] = f2bf(Wih[j * 4 + d] * sc);
                float bias = (l < 2) ? (bih[j] + bhh[j]) : bih[j];
                fu.s[4] = f2bf(bias * sc);
            }
            WAUG[l] = fu.v;
        }
#pragma unroll
        for (int r = 0; r < 4; ++r)
            bhhn4[r] = bhh[128 + 16 * w + 4 * q + r] * kL2E2;
    };

    auto make_baug = [&]() -> bf16x8 {
        FragU fu;
        unsigned int p01 = packbf(px[0], px[1]);
        unsigned int p23 = packbf(px[2], px[3]);
        fu.u32[0] = q0 ? p01 : 0u;
        fu.u32[1] = q0 ? p23 : 0u;
        fu.u32[2] = q0 ? 0x3f80u : 0u;  // bf16(1.0) -> bias column
        fu.u32[3] = 0u;
        return fu.v;
    };

    // One GRU step: compute h' for this wave's 16 units, exchange via LDS
    // (1 barrier), reload full-h B-frags.
    auto gru_step = [&](bf16x8 baug) {
        unsigned short* __restrict__ hw = hbuf[sel];
        f32x4 accR = __builtin_amdgcn_mfma_f32_16x16x32_bf16(WAUG[0], baug, z4, 0, 0, 0);
        accR = __builtin_amdgcn_mfma_f32_16x16x32_bf16(WA[0][0], bh0, accR, 0, 0, 0);
        accR = __builtin_amdgcn_mfma_f32_16x16x32_bf16(WA[0][1], bh1, accR, 0, 0, 0);
        f32x4 accZ = __builtin_amdgcn_mfma_f32_16x16x32_bf16(WAUG[1], baug, z4, 0, 0, 0);
        accZ = __builtin_amdgcn_mfma_f32_16x16x32_bf16(WA[1][0], bh0, accZ, 0, 0, 0);
        accZ = __builtin_amdgcn_mfma_f32_16x16x32_bf16(WA[1][1], bh1, accZ, 0, 0, 0);
        f32x4 accNi = __builtin_amdgcn_mfma_f32_16x16x32_bf16(WAUG[2], baug, z4, 0, 0, 0);
        f32x4 accNh = __builtin_amdgcn_mfma_f32_16x16x32_bf16(WA[2][0], bh0, bhhn4, 0, 0, 0);
        accNh = __builtin_amdgcn_mfma_f32_16x16x32_bf16(WA[2][1], bh1, accNh, 0, 0, 0);

        float hv[4];
#pragma unroll
        for (int r = 0; r < 4; ++r) {
            // a = 2^-xr, b = 2^-xz; shared rcp for both sigmoids
            float a = __builtin_amdgcn_exp2f(-accR[r]);
            float bb = __builtin_amdgcn_exp2f(-accZ[r]);
            float A = 1.f + a;
            float Bv = 1.f + bb;
            float rp = __builtin_amdgcn_rcpf(A * Bv);
            float rr = rp * Bv;   // sigmoid(xr)
            float zz = rp * A;    // sigmoid(xz)
            // tanh(pre) with pre2 = 2*log2e*pre: 1 - 2/(2^pre2 + 1)
            float pre2 = __builtin_fmaf(rr, accNh[r], accNi[r]);
            float tt = __builtin_amdgcn_rcpf(__builtin_amdgcn_exp2f(pre2) + 1.f);
            float nn = __builtin_fmaf(-2.f, tt, 1.f);
            float hp = hprev[r];
            hv[r] = __builtin_fmaf(zz, hp - nn, nn);  // (1-z)n + z h
            hprev[r] = hv[r];
        }
        uint2 wv;
        wv.x = packbf(hv[0], hv[1]);
        wv.y = packbf(hv[2], hv[3]);
        *(uint2*)&hw[i * 68 + 16 * w + 4 * q] = wv;  // h'[b=i][u=16w+4q..+3]

        __syncthreads();  // h' slices visible block-wide
        FragU f0, f1;
        f0.u64[0] = *(const unsigned long long*)&hw[i * 68 + 8 * q];
        f0.u64[1] = *(const unsigned long long*)&hw[i * 68 + 8 * q + 4];
        f1.u64[0] = *(const unsigned long long*)&hw[i * 68 + 32 + 8 * q];
        f1.u64[1] = *(const unsigned long long*)&hw[i * 68 + 32 + 8 * q + 4];
        bh0 = f0.v;
        bh1 = f1.v;
        sel ^= 1;
    };

    // ---------------- encoder ----------------
#pragma unroll
    for (int r = 0; r < 4; ++r) hprev[r] = 0.f;
    load_whh(eWhh);
    load_aug(eWih, ebih, ebhh);

    float4 xp = *(const float4*)(xrow);
    float4 xn = *(const float4*)(xrow + 4);
#pragma unroll 1
    for (int s = 0; s < kT - 1; ++s) {
        int idx = s + 2; if (idx > kT - 1) idx = kT - 1;
        float4 xf = *(const float4*)(xrow + idx * 4);
        px[0] = xn.x - xp.x;
        px[1] = xn.y - xp.y;
        px[2] = xn.z - xp.z;
        px[3] = xn.w - xp.w;
        gru_step(make_baug());
        xp = xn;
        xn = xf;
    }
    float4 offv = xp;  // input[b][T-1]; px = diffs[b][T-2]

    // ---------------- decoder ----------------
    load_whh(dWhh);
    load_aug(dWih, dbih, dbhh);

    // linear head frags (held by ALL waves; head computed redundantly so the
    // fp32 px chain stays wave-local; values only meaningful on q0 lanes)
    bf16x8 AL0, AL1, AL2;
    {
        FragU a0, a1, a2;
        a0.u64[0] = a0.u64[1] = 0;
        a1.u64[0] = a1.u64[1] = 0;
        a2.u64[0] = a2.u64[1] = 0;
        if (i < 4) {
            const float* p0 = linW + i * 64 + q * 8;
            const float* p1 = linW + i * 64 + 32 + q * 8;
#pragma unroll
            for (int j = 0; j < 8; ++j) {
                a0.s[j] = f2bf(p0[j]);
                a1.s[j] = f2bf(p1[j]);
            }
            if (q0) a2.s[4] = f2bf(linb[i]);
        }
        AL0 = a0.v; AL1 = a1.v; AL2 = a2.v;
    }

#pragma unroll 1
    for (int s = 0; s < kOut; ++s) {
        bf16x8 baug = make_baug();
        gru_step(baug);  // bh0/bh1 = NEW full h
        f32x4 accX = __builtin_amdgcn_mfma_f32_16x16x32_bf16(AL2, baug, z4, 0, 0, 0);
        accX = __builtin_amdgcn_mfma_f32_16x16x32_bf16(AL0, bh0, accX, 0, 0, 0);
        accX = __builtin_amdgcn_mfma_f32_16x16x32_bf16(AL1, bh1, accX, 0, 0, 0);
        // q0 lanes: accX[r] = x_d for d=r, col=i=batch. fp32 px chain.
        float x0 = accX[0] + px[0];
        float x1 = accX[1] + px[1];
        float x2 = accX[2] + px[2];
        float x3 = accX[3] + px[3];
        if (w == 0 && q0) {
            float* sr = sout + i * 84 + s * 4;
            sr[0] = x0 + offv.x;
            sr[1] = x1 + offv.y;
            sr[2] = x2 + offv.z;
            sr[3] = x3 + offv.w;
        }
        px[0] = x0; px[1] = x1; px[2] = x2; px[3] = x3;
    }

    // coalesced flush: wave 0 writes this block's 16 rows x 80 floats.
    // sout was written by this same wave -> no extra barrier needed.
    if (w == 0) {
        float* __restrict__ go = out + (long)blockIdx.x * 16 * (kOut * 4);
#pragma unroll
        for (int it = 0; it < 5; ++it) {
            int g = it * 256 + lane * 4;
            int row = g / 80;
            int e = g - row * 80;
            float4 v = *(const float4*)&sout[row * 84 + e];
            *(float4*)&go[g] = v;
        }
    }
}

}  // namespace

extern "C" void kernel_launch(void* const* d_in, const int* in_sizes, int n_in,
                              void* d_out, int out_size, void* d_ws, size_t ws_size,
                              hipStream_t stream) {
    const float* input = (const float*)d_in[0];
    const float* eWih = (const float*)d_in[1];
    const float* eWhh = (const float*)d_in[2];
    const float* ebih = (const float*)d_in[3];
    const float* ebhh = (const float*)d_in[4];
    const float* dWih = (const float*)d_in[5];
    const float* dWhh = (const float*)d_in[6];
    const float* dbih = (const float*)d_in[7];
    const float* dbhh = (const float*)d_in[8];
    const float* linW = (const float*)d_in[9];
    const float* linb = (const float*)d_in[10];
    float* out = (float*)d_out;

    const int B = in_sizes[0] / (kT * 4);
    const int nblocks = B / 16;
    gru_encdec<<<nblocks, 256, 0, stream>>>(input, eWih, eWhh, ebih, ebhh,
                                            dWih, dWhh, dbih, dbhh,
                                            linW, linb, out);
}

// Round 6
// 658.956 us; speedup vs baseline: 1.0498x; 1.0498x over previous
//
#include <hip/hip_runtime.h>
#include <hip/hip_bf16.h>

namespace {

constexpr int kT = 51;      // input timesteps
constexpr int kOut = 20;    // decoder steps
constexpr float kL2E  = 1.4426950408889634f;   // log2(e)
constexpr float kL2E2 = 2.8853900817779268f;   // 2*log2(e)

typedef __attribute__((ext_vector_type(8))) short bf16x8;
typedef __attribute__((ext_vector_type(4))) float f32x4;

union FragU {
    bf16x8 v;
    unsigned long long u64[2];
    unsigned int u32[4];
    unsigned short s[8];
};

__device__ __forceinline__ unsigned short f2bf(float x) {
    union { float f; unsigned int u; } v;
    v.f = x;
    unsigned int r = (v.u + 0x7fffu + ((v.u >> 16) & 1u)) >> 16;
    return (unsigned short)r;
}

// pack two floats to bf16x2 (low=bf(a), high=bf(b)): 2x v_add_u32 + v_perm_b32
__device__ __forceinline__ unsigned int packbf(float a, float b) {
    union { float f; unsigned int u; } ua, ub;
    ua.f = a; ub.f = b;
    return __builtin_amdgcn_perm(ub.u + 0x8000u, ua.u + 0x8000u, 0x07060302u);
}

// GRU enc-dec, 4-way unit split x 2 batch groups. Block = 256 thr = 4 waves,
// handling 32 batch rows (groups g=0,1 of 16). Wave w owns hidden units
// [16w,16w+16) for BOTH groups (weight frags shared). h' slices exchanged via
// double-buffered LDS, one __syncthreads per step.
// MFMA 16x16x32 layouts: A lane(q,i)=A[m=i][k=8q+j]; B lane(q,i)=B[k=8q+j][n=i];
// C lane(q,i)=C[row=4q+r][col=i]. Weights pre-scaled by log2e (r,z) / 2log2e
// (n) so activations use raw v_exp_f32. Rcp product-sharing pairs group0/group1
// units: 4 trans/unit (3 exp2 + 1 rcp).
__global__ __launch_bounds__(256, 3) void gru_encdec(
    const float* __restrict__ input,
    const float* __restrict__ eWih, const float* __restrict__ eWhh,
    const float* __restrict__ ebih, const float* __restrict__ ebhh,
    const float* __restrict__ dWih, const float* __restrict__ dWhh,
    const float* __restrict__ dbih, const float* __restrict__ dbhh,
    const float* __restrict__ linW, const float* __restrict__ linb,
    float* __restrict__ out)
{
    // h exchange: [dbuf][group][16 rows x 64 units, stride 68 bf16]
    __shared__ __align__(16) unsigned short hbuf[2][2][16 * 68];
    // decoder output staging: [group][16 rows x 80 floats, stride 84]
    __shared__ __align__(16) float sout[2][16 * 84];

    const int lane = (int)(threadIdx.x & 63u);
    const int w = (int)(threadIdx.x >> 6u);   // unit-quarter owner
    const int q = lane >> 4;
    const int i = lane & 15;
    const long b0 = (long)blockIdx.x * 32 + i;        // group 0 batch row
    const float* __restrict__ xrow0 = input + b0 * (kT * 4);
    const float* __restrict__ xrow1 = xrow0 + 16 * (kT * 4);
    const bool q0 = (q == 0);

    // Per-wave weight fragments: l = 0 (r), 1 (z), 2 (n); tau = 4*l + w
    bf16x8 WA[3][2];     // Whh frags, [l][K-half]
    bf16x8 WAUG[3];      // [Wih(4) | bias | 0...] frags (q0 lanes meaningful)
    f32x4 bhhn4;         // bhh_n * 2l2e as C-init
    float hp0[4], hp1[4];           // fp32 h per group, [r]=h[b][u=16w+4q+r]
    bf16x8 bhA0 = {0,0,0,0,0,0,0,0}, bhB0 = {0,0,0,0,0,0,0,0};  // g0 B-frags
    bf16x8 bhA1 = {0,0,0,0,0,0,0,0}, bhB1 = {0,0,0,0,0,0,0,0};  // g1 B-frags
    float px0[4], px1[4];
    const f32x4 z4 = {0.f, 0.f, 0.f, 0.f};

    auto load_whh = [&](const float* __restrict__ Whh) {
#pragma unroll
        for (int l = 0; l < 3; ++l) {
            const int tau = 4 * l + w;
            const float sc = (l < 2) ? kL2E : kL2E2;
#pragma unroll
            for (int f = 0; f < 2; ++f) {
                const float* ptr = Whh + (tau * 16 + i) * 64 + f * 32 + q * 8;
                FragU fu;
#pragma unroll
                for (int j = 0; j < 8; ++j) fu.s[j] = f2bf(ptr[j] * sc);
                WA[l][f] = fu.v;
            }
        }
    };

    auto load_aug = [&](const float* __restrict__ Wih,
                        const float* __restrict__ bih,
                        const float* __restrict__ bhh) {
#pragma unroll
        for (int l = 0; l < 3; ++l) {
            const int tau = 4 * l + w;
            const float sc = (l < 2) ? kL2E : kL2E2;
            FragU fu;
            fu.u64[0] = 0; fu.u64[1] = 0;
            if (q0) {
                int j = tau * 16 + i;
#pragma unroll
                for (int d = 0; d < 4; ++d) fu.s[d] = f2bf(Wih[j * 4 + d] * sc);
                float bias = (l < 2) ? (bih[j] + bhh[j]) : bih[j];
                fu.s[4] = f2bf(bias * sc);
            }
            WAUG[l] = fu.v;
        }
#pragma unroll
        for (int r = 0; r < 4; ++r)
            bhhn4[r] = bhh[128 + 16 * w + 4 * q + r] * kL2E2;
    };

    // B-frag from px: only k<5 rows are multiplied by nonzero A cols, so no
    // lane masking needed (q>0 lanes / s[5..7] hit zero A columns).
    auto make_baug = [&](const float* px) -> bf16x8 {
        FragU fu;
        fu.u32[0] = packbf(px[0], px[1]);
        fu.u32[1] = packbf(px[2], px[3]);
        fu.u32[2] = 0x3f80u;  // bf16(1.0) -> bias column
        fu.u32[3] = 0u;
        return fu.v;
    };

    // One GRU step for both groups; ssel = LDS dbuf (0/1).
    auto gru_step2 = [&](int ssel, bf16x8 ba0, bf16x8 ba1) {
        unsigned short* __restrict__ hw0 = hbuf[ssel][0];
        unsigned short* __restrict__ hw1 = hbuf[ssel][1];
        // group 0 gates
        f32x4 R0 = __builtin_amdgcn_mfma_f32_16x16x32_bf16(WAUG[0], ba0, z4, 0, 0, 0);
        R0 = __builtin_amdgcn_mfma_f32_16x16x32_bf16(WA[0][0], bhA0, R0, 0, 0, 0);
        R0 = __builtin_amdgcn_mfma_f32_16x16x32_bf16(WA[0][1], bhB0, R0, 0, 0, 0);
        f32x4 Z0 = __builtin_amdgcn_mfma_f32_16x16x32_bf16(WAUG[1], ba0, z4, 0, 0, 0);
        Z0 = __builtin_amdgcn_mfma_f32_16x16x32_bf16(WA[1][0], bhA0, Z0, 0, 0, 0);
        Z0 = __builtin_amdgcn_mfma_f32_16x16x32_bf16(WA[1][1], bhB0, Z0, 0, 0, 0);
        f32x4 Ni0 = __builtin_amdgcn_mfma_f32_16x16x32_bf16(WAUG[2], ba0, z4, 0, 0, 0);
        f32x4 Nh0 = __builtin_amdgcn_mfma_f32_16x16x32_bf16(WA[2][0], bhA0, bhhn4, 0, 0, 0);
        Nh0 = __builtin_amdgcn_mfma_f32_16x16x32_bf16(WA[2][1], bhB0, Nh0, 0, 0, 0);
        // group 1 gates
        f32x4 R1 = __builtin_amdgcn_mfma_f32_16x16x32_bf16(WAUG[0], ba1, z4, 0, 0, 0);
        R1 = __builtin_amdgcn_mfma_f32_16x16x32_bf16(WA[0][0], bhA1, R1, 0, 0, 0);
        R1 = __builtin_amdgcn_mfma_f32_16x16x32_bf16(WA[0][1], bhB1, R1, 0, 0, 0);
        f32x4 Z1 = __builtin_amdgcn_mfma_f32_16x16x32_bf16(WAUG[1], ba1, z4, 0, 0, 0);
        Z1 = __builtin_amdgcn_mfma_f32_16x16x32_bf16(WA[1][0], bhA1, Z1, 0, 0, 0);
        Z1 = __builtin_amdgcn_mfma_f32_16x16x32_bf16(WA[1][1], bhB1, Z1, 0, 0, 0);
        f32x4 Ni1 = __builtin_amdgcn_mfma_f32_16x16x32_bf16(WAUG[2], ba1, z4, 0, 0, 0);
        f32x4 Nh1 = __builtin_amdgcn_mfma_f32_16x16x32_bf16(WA[2][0], bhA1, bhhn4, 0, 0, 0);
        Nh1 = __builtin_amdgcn_mfma_f32_16x16x32_bf16(WA[2][1], bhB1, Nh1, 0, 0, 0);

        float hv0[4], hv1[4];
#pragma unroll
        for (int r = 0; r < 4; ++r) {
            // paired units (g0,r) and (g1,r): shared rcps via product trick
            float a0 = __builtin_amdgcn_exp2f(-R0[r]);
            float c0 = __builtin_amdgcn_exp2f(-Z0[r]);
            float a1 = __builtin_amdgcn_exp2f(-R1[r]);
            float c1 = __builtin_amdgcn_exp2f(-Z1[r]);
            float A0 = 1.f + a0, C0 = 1.f + c0, P0 = A0 * C0;
            float A1 = 1.f + a1, C1 = 1.f + c1, P1 = A1 * C1;
            float rpp = __builtin_amdgcn_rcpf(P0 * P1);
            float rp0 = rpp * P1, rp1 = rpp * P0;
            float rr0 = rp0 * C0, zz0 = rp0 * A0;   // sigmoid(xr0), sigmoid(xz0)
            float rr1 = rp1 * C1, zz1 = rp1 * A1;
            float p20 = __builtin_fmaf(rr0, Nh0[r], Ni0[r]);
            float p21 = __builtin_fmaf(rr1, Nh1[r], Ni1[r]);
            float E0 = __builtin_amdgcn_exp2f(p20);
            float E1 = __builtin_amdgcn_exp2f(p21);
            float D0 = E0 + 1.f, D1 = E1 + 1.f;
            float rdd = __builtin_amdgcn_rcpf(D0 * D1);
            float t0 = rdd * D1, t1 = rdd * D0;
            float n0 = __builtin_fmaf(-2.f, t0, 1.f);   // tanh
            float n1 = __builtin_fmaf(-2.f, t1, 1.f);
            hv0[r] = __builtin_fmaf(zz0, hp0[r] - n0, n0);
            hv1[r] = __builtin_fmaf(zz1, hp1[r] - n1, n1);
            hp0[r] = hv0[r];
            hp1[r] = hv1[r];
        }
        uint2 wv0, wv1;
        wv0.x = packbf(hv0[0], hv0[1]); wv0.y = packbf(hv0[2], hv0[3]);
        wv1.x = packbf(hv1[0], hv1[1]); wv1.y = packbf(hv1[2], hv1[3]);
        *(uint2*)&hw0[i * 68 + 16 * w + 4 * q] = wv0;
        *(uint2*)&hw1[i * 68 + 16 * w + 4 * q] = wv1;

        __syncthreads();  // h' slices visible block-wide
        FragU f0, f1, g0f, g1f;
        f0.u64[0]  = *(const unsigned long long*)&hw0[i * 68 + 8 * q];
        f0.u64[1]  = *(const unsigned long long*)&hw0[i * 68 + 8 * q + 4];
        f1.u64[0]  = *(const unsigned long long*)&hw0[i * 68 + 32 + 8 * q];
        f1.u64[1]  = *(const unsigned long long*)&hw0[i * 68 + 32 + 8 * q + 4];
        g0f.u64[0] = *(const unsigned long long*)&hw1[i * 68 + 8 * q];
        g0f.u64[1] = *(const unsigned long long*)&hw1[i * 68 + 8 * q + 4];
        g1f.u64[0] = *(const unsigned long long*)&hw1[i * 68 + 32 + 8 * q];
        g1f.u64[1] = *(const unsigned long long*)&hw1[i * 68 + 32 + 8 * q + 4];
        bhA0 = f0.v;  bhB0 = f1.v;
        bhA1 = g0f.v; bhB1 = g1f.v;
    };

    // ---------------- encoder ----------------
#pragma unroll
    for (int r = 0; r < 4; ++r) { hp0[r] = 0.f; hp1[r] = 0.f; }
    load_whh(eWhh);
    load_aug(eWih, ebih, ebhh);

    float4 xp0 = *(const float4*)(xrow0);
    float4 xn0 = *(const float4*)(xrow0 + 4);
    float4 xp1 = *(const float4*)(xrow1);
    float4 xn1 = *(const float4*)(xrow1 + 4);
#pragma unroll 2
    for (int s = 0; s < kT - 1; ++s) {
        int idx = s + 2; if (idx > kT - 1) idx = kT - 1;
        float4 xf0 = *(const float4*)(xrow0 + idx * 4);
        float4 xf1 = *(const float4*)(xrow1 + idx * 4);
        px0[0] = xn0.x - xp0.x; px0[1] = xn0.y - xp0.y;
        px0[2] = xn0.z - xp0.z; px0[3] = xn0.w - xp0.w;
        px1[0] = xn1.x - xp1.x; px1[1] = xn1.y - xp1.y;
        px1[2] = xn1.z - xp1.z; px1[3] = xn1.w - xp1.w;
        gru_step2(s & 1, make_baug(px0), make_baug(px1));
        xp0 = xn0; xn0 = xf0;
        xp1 = xn1; xn1 = xf1;
    }
    float4 off0 = xp0;  // input[b][T-1] per group; px = diffs[b][T-2]
    float4 off1 = xp1;

    // ---------------- decoder ----------------
    load_whh(dWhh);
    load_aug(dWih, dbih, dbhh);

    // linear head frags (all waves hold them; head computed redundantly so the
    // fp32 px chains stay wave-local and bitwise-identical across waves)
    bf16x8 AL0, AL1, AL2;
    {
        FragU a0, a1, a2;
        a0.u64[0] = a0.u64[1] = 0;
        a1.u64[0] = a1.u64[1] = 0;
        a2.u64[0] = a2.u64[1] = 0;
        if (i < 4) {
            const float* p0 = linW + i * 64 + q * 8;
            const float* p1 = linW + i * 64 + 32 + q * 8;
#pragma unroll
            for (int j = 0; j < 8; ++j) {
                a0.s[j] = f2bf(p0[j]);
                a1.s[j] = f2bf(p1[j]);
            }
            if (q0) a2.s[4] = f2bf(linb[i]);
        }
        AL0 = a0.v; AL1 = a1.v; AL2 = a2.v;
    }

#pragma unroll 2
    for (int s = 0; s < kOut; ++s) {
        bf16x8 ba0 = make_baug(px0);
        bf16x8 ba1 = make_baug(px1);
        gru_step2(s & 1, ba0, ba1);  // bh frags now hold NEW h
        f32x4 X0 = __builtin_amdgcn_mfma_f32_16x16x32_bf16(AL2, ba0, z4, 0, 0, 0);
        X0 = __builtin_amdgcn_mfma_f32_16x16x32_bf16(AL0, bhA0, X0, 0, 0, 0);
        X0 = __builtin_amdgcn_mfma_f32_16x16x32_bf16(AL1, bhB0, X0, 0, 0, 0);
        f32x4 X1 = __builtin_amdgcn_mfma_f32_16x16x32_bf16(AL2, ba1, z4, 0, 0, 0);
        X1 = __builtin_amdgcn_mfma_f32_16x16x32_bf16(AL0, bhA1, X1, 0, 0, 0);
        X1 = __builtin_amdgcn_mfma_f32_16x16x32_bf16(AL1, bhB1, X1, 0, 0, 0);
        // q0 lanes: X[r] = x_d, d=r, col=i=batch. fp32 px chains.
        px0[0] += X0[0]; px0[1] += X0[1]; px0[2] += X0[2]; px0[3] += X0[3];
        px1[0] += X1[0]; px1[1] += X1[1]; px1[2] += X1[2]; px1[3] += X1[3];
        if (w == 0 && q0) {
            float* sr = sout[0] + i * 84 + s * 4;
            sr[0] = px0[0] + off0.x; sr[1] = px0[1] + off0.y;
            sr[2] = px0[2] + off0.z; sr[3] = px0[3] + off0.w;
        }
        if (w == 1 && q0) {
            float* sr = sout[1] + i * 84 + s * 4;
            sr[0] = px1[0] + off1.x; sr[1] = px1[1] + off1.y;
            sr[2] = px1[2] + off1.z; sr[3] = px1[3] + off1.w;
        }
    }

    // coalesced flush: wave w (w<2) writes group w's 16 rows x 80 floats.
    // sout[w] was written by this same wave -> no extra barrier needed.
    if (w < 2) {
        float* __restrict__ go = out + ((long)blockIdx.x * 32 + w * 16) * (kOut * 4);
        const float* __restrict__ so = sout[w];
#pragma unroll
        for (int it = 0; it < 5; ++it) {
            int g = it * 256 + lane * 4;
            int row = g / 80;
            int e = g - row * 80;
            float4 v = *(const float4*)&so[row * 84 + e];
            *(float4*)&go[g] = v;
        }
    }
}

}  // namespace

extern "C" void kernel_launch(void* const* d_in, const int* in_sizes, int n_in,
                              void* d_out, int out_size, void* d_ws, size_t ws_size,
                              hipStream_t stream) {
    const float* input = (const float*)d_in[0];
    const float* eWih = (const float*)d_in[1];
    const float* eWhh = (const float*)d_in[2];
    const float* ebih = (const float*)d_in[3];
    const float* ebhh = (const float*)d_in[4];
    const float* dWih = (const float*)d_in[5];
    const float* dWhh = (const float*)d_in[6];
    const float* dbih = (const float*)d_in[7];
    const float* dbhh = (const float*)d_in[8];
    const float* linW = (const float*)d_in[9];
    const float* linb = (const float*)d_in[10];
    float* out = (float*)d_out;

    const int B = in_sizes[0] / (kT * 4);
    const int nblocks = B / 32;
    gru_encdec<<<nblocks, 256, 0, stream>>>(input, eWih, eWhh, ebih, ebhh,
                                            dWih, dWhh, dbih, dbhh,
                                            linW, linb, out);
}